// Round 12
// baseline (871.290 us; speedup 1.0000x reference)
//
#include <hip/hip_runtime.h>
#include <hip/hip_bf16.h>

typedef unsigned short u16;
typedef unsigned int u32;

// Problem constants (match reference setup_inputs)
static constexpr int cNV = 4096, cEV = 16384, cB = 128, cNC = 32, cNS = 128;
static constexpr int cNSITE = 16384, cES = 131072;
static constexpr int cH = 128, cK8 = 8, cHI = 64;

__device__ __forceinline__ float leakyf(float x){ return x > 0.f ? x : 0.1f * x; }
__device__ __forceinline__ float sigm(float x){ return 1.f / (1.f + __expf(-x)); }

typedef __attribute__((ext_vector_type(4))) short short4v;
typedef __attribute__((ext_vector_type(4))) float f32x4;

__device__ __forceinline__ u16 f2bu(float x){
  __hip_bfloat16 h = __float2bfloat16(x);
  return *(u16*)&h;
}
__device__ __forceinline__ float bf2f(u16 u){
  __hip_bfloat16 h; *(u16*)&h = u;
  return __bfloat162float(h);
}

// ---------------- CSR build ----------------
__global__ void zero_i_k(int* __restrict__ p, int n){
  int i = blockIdx.x * 256 + threadIdx.x;
  if (i < n) p[i] = 0;
}
__global__ void copy_i_k(const int* __restrict__ s, int* __restrict__ d, int n){
  int i = blockIdx.x * 256 + threadIdx.x;
  if (i < n) d[i] = s[i];
}
__global__ void count_k(const int* __restrict__ dst, int* __restrict__ cnt, int ne){
  int i = blockIdx.x * 256 + threadIdx.x;
  if (i < ne) atomicAdd(&cnt[dst[i]], 1);
}
// single-block exclusive scan: off[0..n] from cnt[0..n-1]; n divisible by 256
__global__ void scan_k(const int* __restrict__ cnt, int* __restrict__ off, int n){
  __shared__ int part[256];
  int t = threadIdx.x;
  int chunk = n >> 8;
  int base = t * chunk;
  int s = 0;
  for (int j = 0; j < chunk; j++) s += cnt[base + j];
  part[t] = s;
  __syncthreads();
  for (int d = 1; d < 256; d <<= 1) {
    int v = (t >= d) ? part[t - d] : 0;
    __syncthreads();
    part[t] += v;
    __syncthreads();
  }
  int run = (t == 0) ? 0 : part[t - 1];
  for (int j = 0; j < chunk; j++) { off[base + j] = run; run += cnt[base + j]; }
  if (t == 255) off[n] = run;
}
__global__ void fill_k(const int* __restrict__ src, const int* __restrict__ dst,
                       int* __restrict__ cur, int* __restrict__ perm, int ne){
  int i = blockIdx.x * 256 + threadIdx.x;
  if (i < ne) {
    int p = atomicAdd(&cur[dst[i]], 1);
    perm[p] = src[i];
  }
}

// ---------------- gathers ----------------
__global__ void gather128_f_k(const float* __restrict__ h, const int* __restrict__ off,
                              const int* __restrict__ perm, float* __restrict__ nei){
  int row = blockIdx.x, t = threadIdx.x;
  int b = off[row], e = off[row + 1];
  float s = 0.f;
  for (int i = b; i < e; i++) s += h[(long)perm[i] * 128 + t];
  nei[(long)row * 128 + t] = s;
}
__global__ void gather128_b_k(const u16* __restrict__ h, const int* __restrict__ off,
                              const int* __restrict__ perm, u16* __restrict__ nei){
  int row = blockIdx.x, t = threadIdx.x;
  int b = off[row], e = off[row + 1];
  float s = 0.f;
  for (int i = b; i < e; i++) s += bf2f(h[(long)perm[i] * 128 + t]);
  nei[(long)row * 128 + t] = f2bu(s);
}
__global__ void gather32_k(const float* __restrict__ h, const int* __restrict__ off,
                           const int* __restrict__ perm, u16* __restrict__ nei){
  int t = threadIdx.x;
  int row = blockIdx.x * 8 + (t >> 5), c = t & 31;
  int b = off[row], e = off[row + 1];
  float s = 0.f;
  for (int i = b; i < e; i++) s += h[(long)perm[i] * 32 + c];
  nei[(long)row * 32 + c] = f2bu(s);
}

// transpose+convert weight: dst[n*Kr + k] = bf16(src[k*ldw + (n>>cshift)*cs + (n&mask)])
__global__ void cvtw_k(const float* __restrict__ src, u16* __restrict__ dst,
                       int K, int krsh, int N, int ldw, int cshift, int cs){
  long i = (long)blockIdx.x * 256 + threadIdx.x;
  int Kr = 1 << krsh;
  if (i >= (long)N * Kr) return;
  int n = (int)(i >> krsh), k = (int)(i & (Kr - 1));
  float v = 0.f;
  if (k < K) v = src[(long)k * ldw + (long)(n >> cshift) * cs + (n & ((1 << cshift) - 1))];
  dst[i] = f2bu(v);
}

// ---------------- grouped MFMA GEMM (bf16 storage, templated M-tile) ----------------
struct GSegs {
  const u16* Wt[4];
  const float* bias[4];
  const float* addA[4];   // optional f32 add, stride K (slow path)
  void* C[4];
  u16* C2[4];
  int nb_end[4];
  int N[4];
  int Kr[4];
  int act[4];
  int odt[4];
  int nsegs;
};

template<int MT>
__global__ __launch_bounds__(256) void gemm_g(
    const void* __restrict__ A0, const void* __restrict__ A1,
    const void* __restrict__ A2, const void* __restrict__ A3,
    int dt0, int dt1, int dt2, int dt3,
    int k1, int k2, int k3, int K, int M,
    GSegs segs, const float* __restrict__ ep1, const float* __restrict__ ep2)
{
  constexpr int RPW = MT / 32;        // row fragments per wave (2 or 4)
  constexpr int TPR = 256 / MT;       // threads per A row (4 or 2)
  constexpr int ASUB = MT / 16;       // 8-wide A sub-chunks per thread (4 or 8)
  __shared__ __align__(16) u16 As[MT * 136];
  __shared__ __align__(16) u16 Bs[64 * 136];
  const int t = threadIdx.x;
  const int l = t & 63, w = t >> 6;
  const int wrh = w >> 1, wc = w & 1;
  const int lr = l & 15, lh = l >> 4;

  const int nwg = gridDim.x * gridDim.y;
  const int bid = blockIdx.y * gridDim.x + blockIdx.x;
  const int cpx = nwg >> 3;
  const int swz = (bid & 7) * cpx + (bid >> 3);
  const int bx = swz % gridDim.x, by = swz / gridDim.x;

  const u16* Wt = nullptr; const float* bias = nullptr; const float* addA = nullptr;
  void* C = nullptr; u16* C2 = nullptr;
  int Nn = 0, Kr = 0, act = 0, odt = 0, nb0 = 0;
  {
    int nbs = 0;
    #pragma unroll
    for (int s = 0; s < 4; s++) {
      if (s < segs.nsegs) {
        int e = segs.nb_end[s];
        if (bx >= nbs && bx < e) {
          Wt = segs.Wt[s]; bias = segs.bias[s]; addA = segs.addA[s];
          C = segs.C[s]; C2 = segs.C2[s];
          Nn = segs.N[s]; Kr = segs.Kr[s]; act = segs.act[s]; odt = segs.odt[s];
          nb0 = nbs;
        }
        nbs = e;
      }
    }
  }
  const int n0 = (bx - nb0) * 64;
  const int m0 = by * MT;
  const int w1 = k2 - k1, w2 = k3 - k2, w3 = K - k3;

  f32x4 acc[RPW][2];
  #pragma unroll
  for (int i = 0; i < RPW; i++)
    #pragma unroll
    for (int j = 0; j < 2; j++)
      acc[i][j] = (f32x4){0.f, 0.f, 0.f, 0.f};

  const int arow = t / TPR, ak0 = (t % TPR) * (128 / TPR);
  const int bcol = t & 63, bq = (t >> 6) * 32;
  const int mg = m0 + arow;

  for (int kt = 0; kt < K; kt += 128) {
    // ---- stage A (MT rows x 128 k) ----
    #pragma unroll
    for (int sub = 0; sub < ASUB; sub++) {
      const int kg0 = kt + ak0 + sub * 8;
      const void* bp; int st, wseg, dt;
      if (kg0 < k1)      { bp = A0; st = 0;  wseg = k1; dt = dt0; }
      else if (kg0 < k2) { bp = A1; st = k1; wseg = w1; dt = dt1; }
      else if (kg0 < k3) { bp = A2; st = k2; wseg = w2; dt = dt2; }
      else               { bp = A3; st = k3; wseg = w3; dt = dt3; }
      uint4 v;
      if (dt == 0 && addA == nullptr && kg0 + 8 <= st + wseg) {
        v = *(const uint4*)((const u16*)bp + (long)mg * wseg + (kg0 - st));
      } else {
        float f[8];
        #pragma unroll
        for (int j = 0; j < 8; j++) {
          int kg = kg0 + j;
          float x = 0.f;
          if (kg < K) {
            long o = (long)mg * wseg + (kg - st);
            x = dt ? ((const float*)bp)[o] : bf2f(((const u16*)bp)[o]);
            if (addA != nullptr) x += addA[(long)mg * K + kg];
          }
          f[j] = x;
        }
        v.x = (u32)f2bu(f[0]) | ((u32)f2bu(f[1]) << 16);
        v.y = (u32)f2bu(f[2]) | ((u32)f2bu(f[3]) << 16);
        v.z = (u32)f2bu(f[4]) | ((u32)f2bu(f[5]) << 16);
        v.w = (u32)f2bu(f[6]) | ((u32)f2bu(f[7]) << 16);
      }
      *(uint4*)&As[arow * 136 + ak0 + sub * 8] = v;
    }
    // ---- stage B (64 cols x 128 k) ----
    #pragma unroll
    for (int sub = 0; sub < 4; sub++) {
      uint4 v = *(const uint4*)(Wt + (long)(n0 + bcol) * Kr + kt + bq + sub * 8);
      *(uint4*)&Bs[bcol * 136 + bq + sub * 8] = v;
    }
    __syncthreads();
    // ---- compute ----
    #pragma unroll
    for (int ks = 0; ks < 8; ks++) {
      short4v b0 = *(short4v*)&Bs[(wc * 32 + 0 * 16 + lr) * 136 + ks * 16 + lh * 4];
      short4v b1 = *(short4v*)&Bs[(wc * 32 + 1 * 16 + lr) * 136 + ks * 16 + lh * 4];
      #pragma unroll
      for (int ri = 0; ri < RPW; ri++) {
        short4v a = *(short4v*)&As[(wrh * (MT / 2) + ri * 16 + lr) * 136 + ks * 16 + lh * 4];
        acc[ri][0] = __builtin_amdgcn_mfma_f32_16x16x16bf16_1k(a, b0, acc[ri][0], 0, 0, 0);
        acc[ri][1] = __builtin_amdgcn_mfma_f32_16x16x16bf16_1k(a, b1, acc[ri][1], 0, 0, 0);
      }
    }
    __syncthreads();
  }
  // ---- epilogue ----
  #pragma unroll
  for (int ri = 0; ri < RPW; ri++) {
    #pragma unroll
    for (int ci = 0; ci < 2; ci++) {
      int col = n0 + wc * 32 + ci * 16 + lr;
      float bv = (bias != nullptr) ? bias[col] : 0.f;
      #pragma unroll
      for (int e = 0; e < 4; e++) {
        int row = m0 + wrh * (MT / 2) + ri * 16 + lh * 4 + e;
        float v = acc[ri][ci][e] + bv;
        if (act == 1) v = leakyf(v);
        else if (act == 2) v = tanhf(v);
        else if (act == 3) v = sigm(v);
        else if (act == 4) {
          int b = row >> 5;
          float zm = sigm(v + ep1[b * 128 + col]);
          float msv = bf2f(((const u16*)A0)[(long)row * k1 + col]);
          v = (1.f - zm) * msv + zm * ep2[b * 128 + col];
        }
        long o = (long)row * Nn + col;
        if (odt == 0) ((float*)C)[o] = v;
        else if (odt == 1) ((u16*)C)[o] = f2bu(v);
        else { ((float*)C)[o] = v; C2[o] = f2bu(v); }
      }
    }
  }
}

// ---------------- compound-graph kernels ----------------
__global__ void supe_init_k(const float* __restrict__ vert, float* __restrict__ supe){
  int b = blockIdx.x, c = threadIdx.x;
  float s = 0.f;
  for (int i = 0; i < cNC; i++) s += vert[(b * cNC + i) * cH + c];
  supe[b * cH + c] = s;
}

__global__ __launch_bounds__(256) void supe_pre_k(
    const float* __restrict__ supe,
    const float* __restrict__ Wa_super_d, const float* __restrict__ Ws2m_d,
    const float* __restrict__ Wzm2_d, const float* __restrict__ Wsup_d,
    const float* __restrict__ Whh_s, const float* __restrict__ bhh_s,
    float* __restrict__ asup, float* __restrict__ s2m, float* __restrict__ s2mz,
    float* __restrict__ sself, float* __restrict__ gh_s)
{
  __shared__ float srow[cH];
  __shared__ float s2ml[cH];
  int b = blockIdx.x, t = threadIdx.x;
  if (t < cH) srow[t] = supe[b * cH + t];
  __syncthreads();
  for (int j = 0; j < 4; j++) {
    int c = t + j * 256;
    int head = c >> 7, e = c & 127;
    const float* Wp = Wa_super_d + head * 16384 + e;
    float s = 0.f;
    for (int d2 = 0; d2 < cH; d2++) s += srow[d2] * Wp[d2 * 128];
    asup[b * 1024 + c] = tanhf(s);
  }
  if (t < cH) {
    float s = 0.f;
    for (int d2 = 0; d2 < cH; d2++) s += srow[d2] * Ws2m_d[d2 * 128 + t];
    float v = tanhf(s);
    s2ml[t] = v; s2m[b * cH + t] = v;
  } else {
    int c = t - cH;
    float s = 0.f;
    for (int d2 = 0; d2 < cH; d2++) s += srow[d2] * Wsup_d[d2 * 128 + c];
    sself[b * cH + c] = tanhf(s);
  }
  {
    int c = t;
    float s = 0.f;
    for (int d2 = 0; d2 < cH; d2++) s += srow[d2] * Whh_s[d2 * 384 + c];
    gh_s[b * 384 + c] = s + bhh_s[c];
    if (t < cH) {
      int c2 = 256 + t;
      float s2 = 0.f;
      for (int d2 = 0; d2 < cH; d2++) s2 += srow[d2] * Whh_s[d2 * 384 + c2];
      gh_s[b * 384 + c2] = s2 + bhh_s[c2];
    }
  }
  __syncthreads();
  if (t < cH) {
    float s = 0.f;
    for (int d2 = 0; d2 < cH; d2++) s += s2ml[d2] * Wzm2_d[d2 * 128 + t];
    s2mz[b * cH + t] = s;
  }
}

// attention scores + segment softmax (am bf16, vectorized loads)
__global__ __launch_bounds__(256) void attn_k(
    const u16* __restrict__ am, const float* __restrict__ asup,
    const float* __restrict__ Wb_d, float* __restrict__ attn)
{
  __shared__ float pw[1024];
  __shared__ float sc[cNC][cK8];
  int b = blockIdx.x, t = threadIdx.x;
  for (int j = 0; j < 4; j++) {
    int c = t + j * 256;
    pw[c] = asup[b * 1024 + c] * Wb_d[c];
  }
  __syncthreads();
  int nl = t >> 3, k = t & 7;
  int n = b * cNC + nl;
  const u16* ar = am + (long)n * 1024 + k * 128;
  float s = 0.f;
  for (int j = 0; j < 16; j++) {
    uint4 v = *(const uint4*)(ar + j * 8);
    const float* pr = pw + k * 128 + j * 8;
    s += bf2f(v.x & 0xffff) * pr[0] + bf2f(v.x >> 16) * pr[1]
       + bf2f(v.y & 0xffff) * pr[2] + bf2f(v.y >> 16) * pr[3]
       + bf2f(v.z & 0xffff) * pr[4] + bf2f(v.z >> 16) * pr[5]
       + bf2f(v.w & 0xffff) * pr[6] + bf2f(v.w >> 16) * pr[7];
  }
  sc[nl][k] = s;
  __syncthreads();
  float mx = -1e30f;
  for (int i = 0; i < cNC; i++) mx = fmaxf(mx, sc[i][k]);
  float den = 0.f;
  for (int i = 0; i < cNC; i++) den += __expf(sc[i][k] - mx);
  attn[n * cK8 + k] = __expf(s - mx) / den;
}

// m2s + main_to_super (msg bf16)
__global__ __launch_bounds__(256) void m2s_k(
    const float* __restrict__ attn, const u16* __restrict__ msg,
    const float* __restrict__ Wm2s_d, float* __restrict__ mts)
{
  __shared__ float m2s[1024];
  __shared__ float at[cNC][cK8];
  int b = blockIdx.x, t = threadIdx.x;
  at[t >> 3][t & 7] = attn[(b * cNC + (t >> 3)) * cK8 + (t & 7)];
  __syncthreads();
  for (int j = 0; j < 4; j++) {
    int c = t + j * 256;
    int k = c >> 7;
    float s = 0.f;
    for (int i = 0; i < cNC; i++) s += at[i][k] * bf2f(msg[(long)(b * cNC + i) * 1024 + c]);
    m2s[c] = s;
  }
  __syncthreads();
  if (t < cH) {
    float s = 0.f;
    for (int j = 0; j < 1024; j++) s += m2s[j] * Wm2s_d[j * 128 + t];
    mts[b * cH + t] = tanhf(s);
  }
}

__global__ void ew_gru_k(const u16* __restrict__ gi, const u16* __restrict__ gh,
                         float* __restrict__ h, u16* __restrict__ hb){
  int idx = blockIdx.x * 256 + threadIdx.x;
  if (idx >= cNV * cH) return;
  int n = idx >> 7, c = idx & 127;
  const u16* gir = gi + (long)n * 384;
  const u16* ghr = gh + (long)n * 384;
  float r = sigm(bf2f(gir[c]) + bf2f(ghr[c]));
  float z = sigm(bf2f(gir[128 + c]) + bf2f(ghr[128 + c]));
  float nn = tanhf(bf2f(gir[256 + c]) + r * bf2f(ghr[256 + c]));
  float v = (1.f - z) * nn + z * h[idx];
  h[idx] = v;
  hb[idx] = f2bu(v);
}

__global__ __launch_bounds__(128) void super_upd_k(
    const float* __restrict__ sself, const float* __restrict__ mts,
    const float* __restrict__ gh_s,
    const float* __restrict__ Wzs1_d, const float* __restrict__ Wzs2_d,
    const float* __restrict__ Wih_s, const float* __restrict__ bih_s,
    float* __restrict__ supe)
{
  __shared__ float ss[cH], mt[cH], xs[cH], sr[cH];
  int b = blockIdx.x, t = threadIdx.x;
  ss[t] = sself[b * cH + t];
  mt[t] = mts[b * cH + t];
  sr[t] = supe[b * cH + t];
  __syncthreads();
  float s1 = 0.f, s2 = 0.f;
  for (int d2 = 0; d2 < cH; d2++) {
    s1 += ss[d2] * Wzs1_d[d2 * 128 + t];
    s2 += mt[d2] * Wzs2_d[d2 * 128 + t];
  }
  float zs = sigm(s1 + s2);
  xs[t] = (1.f - zs) * ss[t] + zs * mt[t];
  __syncthreads();
  float g0 = 0.f, g1 = 0.f, g2 = 0.f;
  for (int d2 = 0; d2 < cH; d2++) {
    float x = xs[d2];
    g0 += x * Wih_s[d2 * 384 + t];
    g1 += x * Wih_s[d2 * 384 + 128 + t];
    g2 += x * Wih_s[d2 * 384 + 256 + t];
  }
  g0 += bih_s[t]; g1 += bih_s[128 + t]; g2 += bih_s[256 + t];
  float r = sigm(g0 + gh_s[b * 384 + t]);
  float z = sigm(g1 + gh_s[b * 384 + 128 + t]);
  float nn = tanhf(g2 + r * gh_s[b * 384 + 256 + t]);
  supe[b * cH + t] = (1.f - z) * nn + z * sr[t];
}

// ---------------- interaction ----------------
__global__ __launch_bounds__(256) void pair_k(
    const u16* __restrict__ pa, const u16* __restrict__ pg, float* __restrict__ out)
{
  __shared__ float pal[cNS][cHI];
  __shared__ float pgl[cNC][cHI + 1];
  int g = blockIdx.x, i = blockIdx.y;
  int t = threadIdx.x;
  for (int l = t; l < cNS * 8; l += 256) {
    int s8 = l >> 3, ch = l & 7;
    uint4 v = *(const uint4*)(pa + (long)(g * cNS + s8) * 448 + i * 64 + ch * 8);
    float* dp = &pal[s8][ch * 8];
    dp[0] = bf2f(v.x & 0xffff); dp[1] = bf2f(v.x >> 16);
    dp[2] = bf2f(v.y & 0xffff); dp[3] = bf2f(v.y >> 16);
    dp[4] = bf2f(v.z & 0xffff); dp[5] = bf2f(v.z >> 16);
    dp[6] = bf2f(v.w & 0xffff); dp[7] = bf2f(v.w >> 16);
  }
  {
    int c = t >> 3, ch = t & 7;
    uint4 v = *(const uint4*)(pg + (long)(g * cNC + c) * 448 + i * 64 + ch * 8);
    float* dp = &pgl[c][ch * 8];
    dp[0] = bf2f(v.x & 0xffff); dp[1] = bf2f(v.x >> 16);
    dp[2] = bf2f(v.y & 0xffff); dp[3] = bf2f(v.y >> 16);
    dp[4] = bf2f(v.z & 0xffff); dp[5] = bf2f(v.z >> 16);
    dp[6] = bf2f(v.w & 0xffff); dp[7] = bf2f(v.w >> 16);
  }
  __syncthreads();
  for (int o = t; o < cNS * cNC; o += 256) {
    int s = o >> 5, c = o & 31;
    float sum = 0.f;
    #pragma unroll 8
    for (int hh = 0; hh < cHI; hh++) sum += pal[s][hh] * pgl[c][hh];
    long p = (long)g * (cNS * cNC) + o;
    out[p * 7 + i] = sum;
  }
}

// ---------------- launch ----------------
extern "C" void kernel_launch(void* const* d_in, const int* in_sizes, int n_in,
                              void* d_out, int out_size, void* d_ws, size_t ws_size,
                              hipStream_t stream) {
  constexpr long OFF_VERT = 0;
  constexpr long OFF_SUPE = 524288;
  constexpr long OFF_SITE = 1064960;
  constexpr long OFF_ATTN = 3162112;
  constexpr long OFF_ASUP = 3194880;
  constexpr long OFF_S2M = 3325952;
  constexpr long OFF_S2MZ = 3342336;
  constexpr long OFF_SSELF = 3358720;
  constexpr long OFF_GHS = 3375104;
  constexpr long OFF_MTS = 3424256;
  constexpr long OFF_NEI = 3440640;
  constexpr long OFF_TMPA = 3964928;
  constexpr long OFF_MS = 4489216;
  constexpr long OFF_ZMP = 5013504;
  constexpr long OFF_XGRU = 5537792;
  constexpr long OFF_GHM = 6062080;
  constexpr long OFF_GIM = 7634944;
  constexpr long OFF_AM = 9207808;
  constexpr long OFF_MSG = 13402112;
  constexpr long OFF_H1 = 17596416;
  constexpr long OFF_H2 = 19693568;
  constexpr long OFF_H3 = 21790720;
  constexpr long WS_FLOATS = 23887872;
  if (ws_size < (size_t)WS_FLOATS * 4) return;

  constexpr long WT_EMB = 0;
  constexpr long WT_SELF = 16384;
  constexpr long WT_AMAIN = 65536;
  constexpr long WT_V = 458752;
  constexpr long WT_HHM = 851968;
  constexpr long WT_ZM1 = 901120;
  constexpr long WT_IHM = 950272;
  constexpr long WT_W0 = 999424;
  constexpr long WT_CONV = 1015808;
  constexpr long WT_OUT = 1081344;
  constexpr long WT_IS = 1146880;
  constexpr long WT_IC = 1204224;

  const float* x_vert  = (const float*)d_in[0];
  const int*   vsrc    = (const int*)d_in[1];
  const int*   vdst    = (const int*)d_in[2];
  const float* W_emb   = (const float*)d_in[4];
  const float* b_emb   = (const float*)d_in[5];
  const float* Wa_main = (const float*)d_in[6];
  const float* Wa_super= (const float*)d_in[7];
  const float* Wv      = (const float*)d_in[8];
  const float* Wb      = (const float*)d_in[9];
  const float* Wm2s    = (const float*)d_in[10];
  const float* Ws2m    = (const float*)d_in[11];
  const float* Wsup    = (const float*)d_in[12];
  const float* Wself   = (const float*)d_in[13];
  const float* Wzm1    = (const float*)d_in[14];
  const float* Wzm2    = (const float*)d_in[15];
  const float* Wzs1    = (const float*)d_in[16];
  const float* Wzs2    = (const float*)d_in[17];
  const float* Wih_m   = (const float*)d_in[18];
  const float* Whh_m   = (const float*)d_in[19];
  const float* bih_m   = (const float*)d_in[20];
  const float* bhh_m   = (const float*)d_in[21];
  const float* Wih_s   = (const float*)d_in[22];
  const float* Whh_s   = (const float*)d_in[23];
  const float* bih_s   = (const float*)d_in[24];
  const float* bhh_s   = (const float*)d_in[25];
  const float* x_site  = (const float*)d_in[26];
  const int*   ssrc    = (const int*)d_in[27];
  const int*   sdst    = (const int*)d_in[28];
  const float* W0      = (const float*)d_in[29];
  const float* b0      = (const float*)d_in[30];
  const float* Wconv   = (const float*)d_in[31];
  const float* bconv   = (const float*)d_in[32];
  const float* Wout    = (const float*)d_in[33];
  const float* bout    = (const float*)d_in[34];
  const float* Wis     = (const float*)d_in[35];
  const float* bis     = (const float*)d_in[36];
  const float* Wic     = (const float*)d_in[37];
  const float* bic     = (const float*)d_in[38];
  float* out = (float*)d_out;

  float* ws = (float*)d_ws;
  float* vert  = ws + OFF_VERT;
  float* supe  = ws + OFF_SUPE;
  float* attn  = ws + OFF_ATTN;
  float* asup  = ws + OFF_ASUP;
  float* s2m   = ws + OFF_S2M;
  float* s2mz  = ws + OFF_S2MZ;
  float* sself = ws + OFF_SSELF;
  float* gh_s  = ws + OFF_GHS;
  float* mts   = ws + OFF_MTS;
  float* nei   = ws + OFF_NEI;

  u16* vert_b = (u16*)(ws + OFF_ZMP);
  u16* ms_b   = (u16*)(ws + OFF_MS);
  u16* xgru_b = (u16*)(ws + OFF_XGRU);
  u16* ghm_b  = (u16*)(ws + OFF_GHM);
  u16* gim_b  = (u16*)(ws + OFF_GHM + 786432);
  u16* h1b    = (u16*)(ws + OFF_H1);
  u16* h2b    = (u16*)(ws + OFF_H2);
  u16* h3b    = (u16*)(ws + OFF_H3);
  u16* site_b = (u16*)(ws + OFF_SITE);
  u16* am_b   = (u16*)(ws + OFF_AM);
  u16* msg_b  = (u16*)(ws + OFF_MSG);
  u16* nei_sb = (u16*)(ws + OFF_AM);
  u16* pa_b   = (u16*)(ws + OFF_MSG);
  u16* pg_b   = (u16*)(ws + OFF_GIM);
  u16* wbuf   = (u16*)(ws + OFF_H3 + 1048576);

  int* iws   = (int*)(ws + OFF_TMPA);
  int* voff  = iws;
  int* vcur  = iws + 8192;
  int* vperm = iws + 16384;
  int* soff  = iws + 32768;
  int* scur  = iws + 57344;
  int* sperm = iws + 81920;

  auto cvtw = [&](const float* src, long wt_off, int K, int krsh, int N,
                  int ldw, int cshift, int cs){
    long tot = (long)N << krsh;
    cvtw_k<<<dim3((unsigned)((tot + 255) / 256)), 256, 0, stream>>>(
        src, wbuf + wt_off, K, krsh, N, ldw, cshift, cs);
  };
  auto gemm1 = [&](const void* A0, int dt0, const void* A1, int dt1,
                   const void* A2, int dt2, const void* A3, int dt3,
                   int k1, int k2, int k3, int K, int M,
                   long wt_off, int Kr, const float* bias,
                   void* C, u16* C2, int N, int act, int odt,
                   const float* addA = nullptr,
                   const float* ep1 = nullptr, const float* ep2 = nullptr){
    GSegs s{};
    s.Wt[0] = wbuf + wt_off; s.bias[0] = bias; s.addA[0] = addA;
    s.C[0] = C; s.C2[0] = C2;
    s.nb_end[0] = N / 64; s.N[0] = N; s.Kr[0] = Kr; s.act[0] = act; s.odt[0] = odt;
    s.nsegs = 1;
    dim3 g(N / 64, M / 64);
    gemm_g<64><<<g, 256, 0, stream>>>(A0, A1, A2, A3, dt0, dt1, dt2, dt3,
                                      k1, k2, k3, K, M, s, ep1, ep2);
  };

  // ---- CSR build (both graphs) ----
  zero_i_k<<<16, 256, 0, stream>>>(vcur, cNV);
  count_k<<<cEV / 256, 256, 0, stream>>>(vdst, vcur, cEV);
  scan_k<<<1, 256, 0, stream>>>(vcur, voff, cNV);
  copy_i_k<<<16, 256, 0, stream>>>(voff, vcur, cNV);
  fill_k<<<cEV / 256, 256, 0, stream>>>(vsrc, vdst, vcur, vperm, cEV);
  zero_i_k<<<64, 256, 0, stream>>>(scur, cNSITE);
  count_k<<<cES / 256, 256, 0, stream>>>(sdst, scur, cES);
  scan_k<<<1, 256, 0, stream>>>(scur, soff, cNSITE);
  copy_i_k<<<64, 256, 0, stream>>>(soff, scur, cNSITE);
  fill_k<<<cES / 256, 256, 0, stream>>>(ssrc, sdst, scur, sperm, cES);

  // ---- one-time weight convert+transpose ----
  cvtw(W_emb, WT_EMB, 82, 7, 128, 128, 30, 0);
  cvtw(Wself, WT_SELF, 128, 7, 384, 128, 7, 16384);
  cvtw(Wa_main, WT_AMAIN, 128, 7, 3072, 128, 7, 16384);
  cvtw(Wv, WT_V, 128, 7, 3072, 128, 7, 16384);
  cvtw(Whh_m, WT_HHM, 128, 7, 384, 384, 30, 0);
  cvtw(Wzm1, WT_ZM1, 128, 7, 384, 128, 7, 16384);
  cvtw(Wih_m, WT_IHM, 128, 7, 384, 384, 30, 0);
  cvtw(W0, WT_W0, 64, 7, 128, 128, 30, 0);
  cvtw(Wconv, WT_CONV, 256, 8, 256, 128, 7, 32768);
  cvtw(Wout, WT_OUT, 416, 9, 128, 128, 30, 0);
  cvtw(Wis, WT_IS, 128, 7, 448, 64, 6, 8192);
  cvtw(Wic, WT_IC, 128, 7, 448, 64, 6, 8192);

  // ---- embedding (dual store) + super init ----
  gemm1(x_vert, 1, x_vert, 1, x_vert, 1, x_vert, 1, 82, 82, 82, 82, cNV,
        WT_EMB, 128, b_emb, vert, vert_b, 128, 1, 2);
  supe_init_k<<<cB, 128, 0, stream>>>(vert, supe);

  // ---- GWM iterations ----
  for (int d = 0; d < 3; d++) {
    const float* Wa_super_d = Wa_super + (long)d * 131072;
    const float* Wb_d = Wb + (long)d * 1024;
    const float* Wm2s_d = Wm2s + (long)d * 131072;
    const float* Ws2m_d = Ws2m + (long)d * 16384;
    const float* Wsup_d = Wsup + (long)d * 16384;
    const float* Wzm2_d = Wzm2 + (long)d * 16384;
    const float* Wzs1_d = Wzs1 + (long)d * 16384;
    const float* Wzs2_d = Wzs2 + (long)d * 16384;

    gather128_f_k<<<cNV, 128, 0, stream>>>(vert, voff, vperm, nei);

    // fused: ms_b | am_b | msg_b | ghm_b  (A=vert_b, K=128, MT=128 tiles)
    {
      GSegs s{};
      s.Wt[0] = wbuf + WT_SELF + (long)d * 16384;  s.bias[0] = nullptr;
      s.addA[0] = nei;     s.C[0] = ms_b;  s.C2[0] = nullptr;
      s.N[0] = 128;  s.Kr[0] = 128; s.act[0] = 1; s.odt[0] = 1; s.nb_end[0] = 2;
      s.Wt[1] = wbuf + WT_AMAIN + (long)d * 131072; s.bias[1] = nullptr;
      s.addA[1] = nullptr; s.C[1] = am_b;  s.C2[1] = nullptr;
      s.N[1] = 1024; s.Kr[1] = 128; s.act[1] = 2; s.odt[1] = 1; s.nb_end[1] = 18;
      s.Wt[2] = wbuf + WT_V + (long)d * 131072;     s.bias[2] = nullptr;
      s.addA[2] = nullptr; s.C[2] = msg_b; s.C2[2] = nullptr;
      s.N[2] = 1024; s.Kr[2] = 128; s.act[2] = 0; s.odt[2] = 1; s.nb_end[2] = 34;
      s.Wt[3] = wbuf + WT_HHM;                      s.bias[3] = bhh_m;
      s.addA[3] = nullptr; s.C[3] = ghm_b; s.C2[3] = nullptr;
      s.N[3] = 384;  s.Kr[3] = 128; s.act[3] = 0; s.odt[3] = 1; s.nb_end[3] = 40;
      s.nsegs = 4;
      dim3 g(40, cNV / 128);
      gemm_g<128><<<g, 256, 0, stream>>>(vert_b, vert_b, vert_b, vert_b, 0, 0, 0, 0,
                                         128, 128, 128, 128, cNV, s, nullptr, nullptr);
    }
    supe_pre_k<<<cB, 256, 0, stream>>>(supe, Wa_super_d, Ws2m_d, Wzm2_d, Wsup_d,
                                       Whh_s, bhh_s, asup, s2m, s2mz, sself, gh_s);
    attn_k<<<cB, 256, 0, stream>>>(am_b, asup, Wb_d, attn);
    m2s_k<<<cB, 256, 0, stream>>>(attn, msg_b, Wm2s_d, mts);
    gemm1(ms_b, 0, ms_b, 0, ms_b, 0, ms_b, 0, 128, 128, 128, 128, cNV,
          WT_ZM1 + (long)d * 16384, 128, nullptr, xgru_b, nullptr, 128, 4, 1,
          nullptr, s2mz, s2m);
    gemm1(xgru_b, 0, xgru_b, 0, xgru_b, 0, xgru_b, 0, 128, 128, 128, 128, cNV,
          WT_IHM, 128, bih_m, gim_b, nullptr, 384, 0, 1);
    ew_gru_k<<<(cNV * cH) / 256, 256, 0, stream>>>(gim_b, ghm_b, vert, vert_b);
    super_upd_k<<<cB, 128, 0, stream>>>(sself, mts, gh_s, Wzs1_d, Wzs2_d,
                                        Wih_s, bih_s, supe);
  }

  // ---- AtomConv on protein sites (CSR gathers, bf16 nei) ----
  gather32_k<<<cNSITE / 8, 256, 0, stream>>>(x_site, soff, sperm, nei_sb);
  gemm1(x_site, 1, nei_sb, 0, nei_sb, 0, nei_sb, 0, 32, 64, 64, 64, cNSITE,
        WT_W0, 128, b0, h1b, nullptr, 128, 1, 1);
  gather128_b_k<<<cNSITE, 128, 0, stream>>>(h1b, soff, sperm, nei_sb);
  gemm1(h1b, 0, nei_sb, 0, nei_sb, 0, nei_sb, 0, 128, 256, 256, 256, cNSITE,
        WT_CONV, 256, bconv, h2b, nullptr, 128, 1, 1);
  gather128_b_k<<<cNSITE, 128, 0, stream>>>(h2b, soff, sperm, nei_sb);
  gemm1(h2b, 0, nei_sb, 0, nei_sb, 0, nei_sb, 0, 128, 256, 256, 256, cNSITE,
        WT_CONV + 32768, 256, bconv + 128, h3b, nullptr, 128, 1, 1);
  gemm1(x_site, 1, h1b, 0, h2b, 0, h3b, 0, 32, 160, 288, 416, cNSITE,
        WT_OUT, 512, bout, site_b, nullptr, 128, 1, 1);

  // ---- Interaction ----
  gemm1(site_b, 0, site_b, 0, site_b, 0, site_b, 0, 128, 128, 128, 128, cNSITE,
        WT_IS, 128, bis, pa_b, nullptr, 448, 1, 1);
  gemm1(vert_b, 0, vert_b, 0, vert_b, 0, vert_b, 0, 128, 128, 128, 128, cNV,
        WT_IC, 128, bic, pg_b, nullptr, 448, 1, 1);
  pair_k<<<dim3(cB, 7), 256, 0, stream>>>(pa_b, pg_b, out);
}